// Round 4
// baseline (1951.306 us; speedup 1.0000x reference)
//
#include <hip/hip_runtime.h>
#include <cmath>

#define T_LEN 512
#define BS    64
#define F_DIM 128
#define HSZ   256
#define DA    64
#define RH    8

// output offsets (floats)
#define OFF_HT   8388608
#define OFF_CT   8404992
#define OFF_ATT  8421376

// ---------------- K1: scores = tanh(x@W1^T + b1)@W2^T + b2 ----------------
__global__ __launch_bounds__(256) void k_scores(
    const float* __restrict__ x, const float* __restrict__ w1,
    const float* __restrict__ b1, const float* __restrict__ w2,
    const float* __restrict__ b2, float* __restrict__ scores)
{
  __shared__ float wl[DA * 129];   // padded stride 129 -> conflict-free
  __shared__ float xs[4][F_DIM];
  __shared__ float hid[4][DA];
  int tid = threadIdx.x;
  for (int id = tid; id < DA * F_DIM; id += 256) {
    int a = id >> 7, f = id & 127;
    wl[a * 129 + f] = w1[id];
  }
  int wv = tid >> 6, lane = tid & 63;
  int pair = blockIdx.x * 4 + wv;          // pair = b*512 + t
  const float* xr = x + (size_t)pair * F_DIM;
  xs[wv][lane]      = xr[lane];
  xs[wv][64 + lane] = xr[64 + lane];
  __syncthreads();
  float acc = b1[lane];
  #pragma unroll 8
  for (int f = 0; f < F_DIM; ++f)
    acc += xs[wv][f] * wl[lane * 129 + f];
  hid[wv][lane] = tanhf(acc);
  __syncthreads();
  if (lane < RH) {
    float sc = b2[lane];
    #pragma unroll 8
    for (int a = 0; a < DA; ++a)
      sc += hid[wv][a] * w2[lane * DA + a];
    scores[(size_t)pair * RH + lane] = sc;
  }
}

// ------- K2: softmax prefix sums -> M (4 t-chunks per batch), attn output -------
// blk: j = blk>>6 (t-chunk 0..3), b = blk&63. Each block is self-consistent:
// softmax shift = max over [0, e). Two-level scan for denominator cumsum.
__global__ __launch_bounds__(512) void k_attn_M(
    const float* __restrict__ x, const float* __restrict__ scores,
    float* __restrict__ M, float* __restrict__ out)
{
  __shared__ float se[T_LEN * 9];
  __shared__ float ivd[T_LEN * 9];
  __shared__ float segsum[RH][65];
  __shared__ float cp[4 * F_DIM * RH];
  __shared__ float gmax[RH];
  int tid = threadIdx.x;
  int blk = blockIdx.x;
  int j = blk >> 6, b = blk & 63;
  int p0 = j * 128, e = p0 + 128;
  int e8 = e * 8;
  const float* sb = scores + (size_t)b * T_LEN * RH;
  for (int id = tid; id < e8; id += 512)
    se[(id >> 3) * 9 + (id & 7)] = sb[id];
  __syncthreads();
  {  // per-r max over [0,e)
    int w = tid >> 6, l = tid & 63;
    float m = -INFINITY;
    for (int t = l; t < e; t += 64)
      m = fmaxf(m, se[t * 9 + w]);
    #pragma unroll
    for (int off = 32; off; off >>= 1)
      m = fmaxf(m, __shfl_xor(m, off));
    if (l == 0) gmax[w] = m;
  }
  __syncthreads();
  for (int id = tid; id < e8; id += 512) {
    int t = id >> 3, r = id & 7;
    se[t * 9 + r] = expf(se[t * 9 + r] - gmax[r]);
  }
  __syncthreads();
  // two-level cumsum of denominators over t<e: 8-t segments
  int nseg = e >> 3;
  {
    int r = tid >> 6, seg = tid & 63;
    if (seg < nseg) {
      float run = 0.f;
      #pragma unroll
      for (int i = 0; i < 8; ++i) {
        int t = seg * 8 + i;
        run += se[t * 9 + r];
        ivd[t * 9 + r] = run;
      }
      segsum[r][seg] = run;
    }
  }
  __syncthreads();
  if (tid < RH) {   // exclusive scan of segment sums (<=64 iters)
    float off = 0.f;
    for (int sg = 0; sg < nseg; ++sg) {
      float tmp = segsum[tid][sg];
      segsum[tid][sg] = off;
      off += tmp;
    }
  }
  __syncthreads();
  for (int id = tid; id < e8; id += 512) {
    int t = id >> 3, r = id & 7;
    ivd[t * 9 + r] = 1.f / (ivd[t * 9 + r] + segsum[r][t >> 3]);
  }
  __syncthreads();
  if (j == 3) {  // attention output (full window), layout [b][r][t]
    for (int id = tid; id < T_LEN * RH; id += 512) {
      int r = id >> 9, t = id & 511;
      out[OFF_ATT + ((size_t)b * RH + r) * T_LEN + t] =
          se[t * 9 + r] * ivd[511 * 9 + r];
    }
  }
  // prefix partials over [0, p0), split 4 ways
  const float* xb = x + (size_t)b * T_LEN * F_DIM;
  {
    int q = tid >> 7, f = tid & 127;
    int len = p0 >> 2;
    int t0 = q * len, t1 = t0 + len;
    float pp[RH];
    #pragma unroll
    for (int r = 0; r < RH; ++r) pp[r] = 0.f;
    for (int t = t0; t < t1; ++t) {
      float xv = xb[t * F_DIM + f];
      #pragma unroll
      for (int r = 0; r < RH; ++r) pp[r] += se[t * 9 + r] * xv;
    }
    float* c = &cp[(q * F_DIM + f) * RH];
    #pragma unroll
    for (int r = 0; r < RH; ++r) c[r] = pp[r];
  }
  __syncthreads();
  if (tid < F_DIM) {  // final 128-t walk for this chunk
    int f = tid;
    float num[RH];
    #pragma unroll
    for (int r = 0; r < RH; ++r) num[r] = 0.f;
    #pragma unroll
    for (int q = 0; q < 4; ++q) {
      const float* c = &cp[(q * F_DIM + f) * RH];
      #pragma unroll
      for (int r = 0; r < RH; ++r) num[r] += c[r];
    }
    float* Mb = M + (size_t)b * T_LEN * F_DIM;
    for (int t = p0; t < e; ++t) {
      float xv = xb[t * F_DIM + f];
      float acc = 0.f;
      #pragma unroll
      for (int r = 0; r < RH; ++r) {
        num[r] += se[t * 9 + r] * xv;
        acc += num[r] * ivd[t * 9 + r];
      }
      Mb[t * F_DIM + f] = 0.125f * acc;
    }
  }
}

// ---------------- K3: recurrent loop, fence-free tagged-atomic sync ----------------
// blk = s*64 + b. On-path work per step = h@Wh only (K=256 split 2-way -> 128 FMA);
// the M@Wi partial for step t+1 (macc) is computed from uniform float4 loads in the
// publish->poll window, fully off the critical path. h travels inside relaxed
// agent-scope 64-bit atomics: (tag=t+1)<<32 | float_bits, parity slot t&1.
__global__ __launch_bounds__(512, 2) void k_lstm(
    const float* __restrict__ M, const float* __restrict__ Wi,
    const float* __restrict__ Wh, const float* __restrict__ bias,
    unsigned long long* __restrict__ slab64,
    float* __restrict__ out)
{
  __shared__ float v[HSZ];       // h_{t-1}
  __shared__ float part[512];
  int tid = threadIdx.x;
  int blk = blockIdx.x;
  int s = blk >> 6;              // col slice
  int b = blk & 63;              // batch
  int half = tid >> 8;
  int ct = tid & 255;
  int type = ct >> 6, jj = ct & 63;
  int col = type * 256 + s * 64 + jj;

  // weights in registers: 64 M-rows + 128 h-rows per thread
  float wm[64], wh[128];
  #pragma unroll
  for (int k = 0; k < 64; ++k)
    wm[k] = Wi[(size_t)(half * 64 + k) * 1024 + col];
  #pragma unroll
  for (int k = 0; k < 128; ++k)
    wh[k] = Wh[(size_t)(half * 128 + k) * 1024 + col];
  float bsum = half ? 0.f : bias[col];
  float c_reg = 0.f;

  if (tid < HSZ) v[tid] = 0.f;

  // macc for t=0
  float macc = bsum;
  {
    const float4* mp = (const float4*)(M + (size_t)b * T_LEN * F_DIM + half * 64);
    #pragma unroll
    for (int k4 = 0; k4 < 16; ++k4) {
      float4 m4 = mp[k4];
      macc += m4.x * wm[4*k4] + m4.y * wm[4*k4+1]
            + m4.z * wm[4*k4+2] + m4.w * wm[4*k4+3];
    }
  }
  __syncthreads();

  int pidx = tid >> 6;
  int sp = pidx + (pidx >= s);   // the 3 partner slices (tid<192)
  int pj = tid & 63;
  int hoff = half * 128;

  for (int t = 0; t < T_LEN; ++t) {
    // --- phase 1 (critical path): h-part ---
    float acc = macc;
    #pragma unroll
    for (int k = 0; k < 128; ++k) acc += v[hoff + k] * wh[k];
    part[tid] = acc;
    __syncthreads();

    // --- phase 2: cell update (wave 0), publish tagged h words ---
    if (tid < 64) {
      float gi = part[tid]       + part[256 + tid];
      float gf = part[64 + tid]  + part[320 + tid];
      float gg = part[128 + tid] + part[384 + tid];
      float go = part[192 + tid] + part[448 + tid];
      float ii = 1.f / (1.f + expf(-gi));
      float ff = 1.f / (1.f + expf(-gf));
      float gt = tanhf(gg);
      float oo = 1.f / (1.f + expf(-go));
      c_reg = ff * c_reg + ii * gt;
      float h = oo * tanhf(c_reg);
      int hsx = s * 64 + tid;
      v[hsx] = h;   // own slice for next step
      unsigned long long pk =
          ((unsigned long long)(unsigned)(t + 1) << 32) |
          (unsigned long long)__float_as_uint(h);
      __hip_atomic_store(&slab64[(((t & 1) * BS + b) * 4 + s) * 64 + tid], pk,
                         __ATOMIC_RELAXED, __HIP_MEMORY_SCOPE_AGENT);
      out[((size_t)b * T_LEN + t) * HSZ + hsx] = h;
      if (t == T_LEN - 1) {
        out[OFF_HT + b * HSZ + hsx] = h;
        out[OFF_CT + b * HSZ + hsx] = c_reg;
      }
    }

    if (t < T_LEN - 1) {
      // --- phase 3 (hidden under wait): macc for t+1, uniform float4 loads ---
      {
        const float4* mp =
            (const float4*)(M + ((size_t)b * T_LEN + t + 1) * F_DIM + half * 64);
        float nm = bsum;
        #pragma unroll
        for (int k4 = 0; k4 < 16; ++k4) {
          float4 m4 = mp[k4];
          nm += m4.x * wm[4*k4] + m4.y * wm[4*k4+1]
              + m4.z * wm[4*k4+2] + m4.w * wm[4*k4+3];
        }
        macc = nm;
      }
      // --- phase 4: poll partner tagged words (no sleep, bare spin) ---
      if (tid < 192) {
        const unsigned long long* addr =
            &slab64[(((t & 1) * BS + b) * 4 + sp) * 64 + pj];
        unsigned want = (unsigned)(t + 1);
        unsigned long long got;
        do {
          got = __hip_atomic_load(addr, __ATOMIC_RELAXED,
                                  __HIP_MEMORY_SCOPE_AGENT);
        } while ((unsigned)(got >> 32) != want);
        v[sp * 64 + pj] = __uint_as_float((unsigned)(got & 0xffffffffu));
      }
      __syncthreads();
    }
  }
}

extern "C" void kernel_launch(void* const* d_in, const int* in_sizes, int n_in,
                              void* d_out, int out_size, void* d_ws, size_t ws_size,
                              hipStream_t stream) {
  const float* x   = (const float*)d_in[0];
  const float* w1  = (const float*)d_in[1];
  const float* b1  = (const float*)d_in[2];
  const float* w2  = (const float*)d_in[3];
  const float* b2  = (const float*)d_in[4];
  const float* Wi  = (const float*)d_in[5];
  const float* Wh  = (const float*)d_in[6];
  const float* bia = (const float*)d_in[7];
  float* out = (float*)d_out;
  float* ws  = (float*)d_ws;

  float* scores = ws;                                    // 262144 f
  float* M      = ws + 262144;                           // 4194304 f
  unsigned long long* slab64 =
      (unsigned long long*)(ws + 262144 + 4194304);      // 2*64*4*64 u64

  hipLaunchKernelGGL(k_scores, dim3(8192), dim3(256), 0, stream,
                     x, w1, b1, w2, b2, scores);
  hipLaunchKernelGGL(k_attn_M, dim3(256), dim3(512), 0, stream,
                     x, scores, M, out);
  hipLaunchKernelGGL(k_lstm, dim3(256), dim3(512), 0, stream,
                     M, Wi, Wh, bia, slab64, out);
}

// Round 5
// 1082.564 us; speedup vs baseline: 1.8025x; 1.8025x over previous
//
#include <hip/hip_runtime.h>
#include <cmath>

#define T_LEN 512
#define BS    64
#define F_DIM 128
#define HSZ   256
#define DA    64
#define RH    8

// output offsets (floats)
#define OFF_HT   8388608
#define OFF_CT   8404992
#define OFF_ATT  8421376

// ---------------- K1: scores = tanh(x@W1^T + b1)@W2^T + b2 ----------------
__global__ __launch_bounds__(256) void k_scores(
    const float* __restrict__ x, const float* __restrict__ w1,
    const float* __restrict__ b1, const float* __restrict__ w2,
    const float* __restrict__ b2, float* __restrict__ scores)
{
  __shared__ float wl[DA * 129];   // padded stride 129 -> conflict-free
  __shared__ float xs[4][F_DIM];
  __shared__ float hid[4][DA];
  int tid = threadIdx.x;
  for (int id = tid; id < DA * F_DIM; id += 256) {
    int a = id >> 7, f = id & 127;
    wl[a * 129 + f] = w1[id];
  }
  int wv = tid >> 6, lane = tid & 63;
  int pair = blockIdx.x * 4 + wv;          // pair = b*512 + t
  const float* xr = x + (size_t)pair * F_DIM;
  xs[wv][lane]      = xr[lane];
  xs[wv][64 + lane] = xr[64 + lane];
  __syncthreads();
  float acc = b1[lane];
  #pragma unroll 8
  for (int f = 0; f < F_DIM; ++f)
    acc += xs[wv][f] * wl[lane * 129 + f];
  hid[wv][lane] = tanhf(acc);
  __syncthreads();
  if (lane < RH) {
    float sc = b2[lane];
    #pragma unroll 8
    for (int a = 0; a < DA; ++a)
      sc += hid[wv][a] * w2[lane * DA + a];
    scores[(size_t)pair * RH + lane] = sc;
  }
}

// ------- K2: softmax prefix sums -> M (4 t-chunks per batch), attn output -------
__global__ __launch_bounds__(512) void k_attn_M(
    const float* __restrict__ x, const float* __restrict__ scores,
    float* __restrict__ M, float* __restrict__ out)
{
  __shared__ float se[T_LEN * 9];
  __shared__ float ivd[T_LEN * 9];
  __shared__ float segsum[RH][65];
  __shared__ float cp[4 * F_DIM * RH];
  __shared__ float gmax[RH];
  int tid = threadIdx.x;
  int blk = blockIdx.x;
  int j = blk >> 6, b = blk & 63;
  int p0 = j * 128, e = p0 + 128;
  int e8 = e * 8;
  const float* sb = scores + (size_t)b * T_LEN * RH;
  for (int id = tid; id < e8; id += 512)
    se[(id >> 3) * 9 + (id & 7)] = sb[id];
  __syncthreads();
  {  // per-r max over [0,e)
    int w = tid >> 6, l = tid & 63;
    float m = -INFINITY;
    for (int t = l; t < e; t += 64)
      m = fmaxf(m, se[t * 9 + w]);
    #pragma unroll
    for (int off = 32; off; off >>= 1)
      m = fmaxf(m, __shfl_xor(m, off));
    if (l == 0) gmax[w] = m;
  }
  __syncthreads();
  for (int id = tid; id < e8; id += 512) {
    int t = id >> 3, r = id & 7;
    se[t * 9 + r] = expf(se[t * 9 + r] - gmax[r]);
  }
  __syncthreads();
  int nseg = e >> 3;
  {
    int r = tid >> 6, seg = tid & 63;
    if (seg < nseg) {
      float run = 0.f;
      #pragma unroll
      for (int i = 0; i < 8; ++i) {
        int t = seg * 8 + i;
        run += se[t * 9 + r];
        ivd[t * 9 + r] = run;
      }
      segsum[r][seg] = run;
    }
  }
  __syncthreads();
  if (tid < RH) {   // exclusive scan of segment sums
    float off = 0.f;
    for (int sg = 0; sg < nseg; ++sg) {
      float tmp = segsum[tid][sg];
      segsum[tid][sg] = off;
      off += tmp;
    }
  }
  __syncthreads();
  for (int id = tid; id < e8; id += 512) {
    int t = id >> 3, r = id & 7;
    ivd[t * 9 + r] = 1.f / (ivd[t * 9 + r] + segsum[r][t >> 3]);
  }
  __syncthreads();
  if (j == 3) {  // attention output (full window), layout [b][r][t]
    for (int id = tid; id < T_LEN * RH; id += 512) {
      int r = id >> 9, t = id & 511;
      out[OFF_ATT + ((size_t)b * RH + r) * T_LEN + t] =
          se[t * 9 + r] * ivd[511 * 9 + r];
    }
  }
  const float* xb = x + (size_t)b * T_LEN * F_DIM;
  {
    int q = tid >> 7, f = tid & 127;
    int len = p0 >> 2;
    int t0 = q * len, t1 = t0 + len;
    float pp[RH];
    #pragma unroll
    for (int r = 0; r < RH; ++r) pp[r] = 0.f;
    for (int t = t0; t < t1; ++t) {
      float xv = xb[t * F_DIM + f];
      #pragma unroll
      for (int r = 0; r < RH; ++r) pp[r] += se[t * 9 + r] * xv;
    }
    float* c = &cp[(q * F_DIM + f) * RH];
    #pragma unroll
    for (int r = 0; r < RH; ++r) c[r] = pp[r];
  }
  __syncthreads();
  if (tid < F_DIM) {
    int f = tid;
    float num[RH];
    #pragma unroll
    for (int r = 0; r < RH; ++r) num[r] = 0.f;
    #pragma unroll
    for (int q = 0; q < 4; ++q) {
      const float* c = &cp[(q * F_DIM + f) * RH];
      #pragma unroll
      for (int r = 0; r < RH; ++r) num[r] += c[r];
    }
    float* Mb = M + (size_t)b * T_LEN * F_DIM;
    for (int t = p0; t < e; ++t) {
      float xv = xb[t * F_DIM + f];
      float acc = 0.f;
      #pragma unroll
      for (int r = 0; r < RH; ++r) {
        num[r] += se[t * 9 + r] * xv;
        acc += num[r] * ivd[t * 9 + r];
      }
      Mb[t * F_DIM + f] = 0.125f * acc;
    }
  }
}

// ---------------- K3: recurrent loop, fence-free tagged-atomic sync ----------------
// blk = s*64 + b. 1024 threads, 4-way K-split: on-path gemv = 96 FMA/thread.
// Disjoint wait-window roles: tid<192 poll ONLY (empty vmcnt queue -> fast detect);
// tid in [512,640) stage M[t+1] (their load stall hides under partner wait).
// h travels inside relaxed agent-scope u64 atomics: (tag=t+1)<<32 | bits, slot t&1.
__global__ __launch_bounds__(1024, 4) void k_lstm(
    const float* __restrict__ M, const float* __restrict__ Wi,
    const float* __restrict__ Wh, const float* __restrict__ bias,
    unsigned long long* __restrict__ slab64,
    float* __restrict__ out)
{
  __shared__ float v[HSZ];       // h_{t-1}
  __shared__ float mst[F_DIM];   // M[b,t,:]
  __shared__ float part[1024];
  int tid = threadIdx.x;
  int blk = blockIdx.x;
  int s = blk >> 6;              // col slice
  int b = blk & 63;              // batch
  int kq = tid >> 8;             // K-quarter (wave-uniform)
  int ct = tid & 255;
  int type = ct >> 6, jj = ct & 63;
  int col = type * 256 + s * 64 + jj;

  // 96 weights per thread, rows kq*96 .. kq*96+95 of [Wi; Wh]
  float w[96];
  #pragma unroll
  for (int k = 0; k < 96; ++k) {
    int kk = kq * 96 + k;
    w[k] = (kk < F_DIM) ? Wi[(size_t)kk * 1024 + col]
                        : Wh[(size_t)(kk - F_DIM) * 1024 + col];
  }
  float bsum = (kq == 0) ? bias[col] : 0.f;
  float c_reg = 0.f;

  if (tid < HSZ) v[tid] = 0.f;
  if (tid >= 512 && tid < 512 + F_DIM)
    mst[tid - 512] = M[(size_t)b * T_LEN * F_DIM + (tid - 512)];
  __syncthreads();

  int pidx = tid >> 6;
  int sp = pidx + (pidx >= s);   // the 3 partner slices (tid<192)
  int pj = tid & 63;

  for (int t = 0; t < T_LEN; ++t) {
    // --- phase 1 (critical path): quarter-gemv, 96 FMA ---
    float acc = bsum;
    if (kq == 0) {
      #pragma unroll
      for (int k = 0; k < 96; ++k) acc += mst[k] * w[k];
    } else if (kq == 1) {
      #pragma unroll
      for (int k = 0; k < 32; ++k) acc += mst[96 + k] * w[k];
      #pragma unroll
      for (int k = 32; k < 96; ++k) acc += v[k - 32] * w[k];
    } else if (kq == 2) {
      #pragma unroll
      for (int k = 0; k < 96; ++k) acc += v[64 + k] * w[k];
    } else {
      #pragma unroll
      for (int k = 0; k < 96; ++k) acc += v[160 + k] * w[k];
    }
    part[tid] = acc;
    __syncthreads();

    // --- phase 2: cell update (wave 0), publish first, then out stores ---
    if (tid < 64) {
      float gi = part[tid]       + part[256 + tid] + part[512 + tid] + part[768 + tid];
      float gf = part[64 + tid]  + part[320 + tid] + part[576 + tid] + part[832 + tid];
      float gg = part[128 + tid] + part[384 + tid] + part[640 + tid] + part[896 + tid];
      float go = part[192 + tid] + part[448 + tid] + part[704 + tid] + part[960 + tid];
      float ii = 1.f / (1.f + __expf(-gi));
      float ff = 1.f / (1.f + __expf(-gf));
      float gt = 1.f - 2.f / (__expf(2.f * gg) + 1.f);
      float oo = 1.f / (1.f + __expf(-go));
      c_reg = ff * c_reg + ii * gt;
      float tc = 1.f - 2.f / (__expf(2.f * c_reg) + 1.f);
      float h = oo * tc;
      int hsx = s * 64 + tid;
      v[hsx] = h;
      unsigned long long pk =
          ((unsigned long long)(unsigned)(t + 1) << 32) |
          (unsigned long long)__float_as_uint(h);
      __hip_atomic_store(&slab64[(((t & 1) * BS + b) * 4 + s) * 64 + tid], pk,
                         __ATOMIC_RELAXED, __HIP_MEMORY_SCOPE_AGENT);
      out[((size_t)b * T_LEN + t) * HSZ + hsx] = h;
      if (t == T_LEN - 1) {
        out[OFF_HT + b * HSZ + hsx] = h;
        out[OFF_CT + b * HSZ + hsx] = c_reg;
      }
    }

    if (t < T_LEN - 1) {
      // --- wait window: stagers (waves 8-9) load M[t+1] straight into LDS ---
      if (tid >= 512 && tid < 512 + F_DIM)
        mst[tid - 512] = M[((size_t)b * T_LEN + t + 1) * F_DIM + (tid - 512)];
      // --- pollers (waves 0-2): bare spin, nothing else in their vmcnt queue ---
      if (tid < 192) {
        const unsigned long long* addr =
            &slab64[(((t & 1) * BS + b) * 4 + sp) * 64 + pj];
        unsigned want = (unsigned)(t + 1);
        unsigned long long got;
        do {
          got = __hip_atomic_load(addr, __ATOMIC_RELAXED,
                                  __HIP_MEMORY_SCOPE_AGENT);
        } while ((unsigned)(got >> 32) != want);
        v[sp * 64 + pj] = __uint_as_float((unsigned)(got & 0xffffffffu));
      }
      __syncthreads();
    }
  }
}

extern "C" void kernel_launch(void* const* d_in, const int* in_sizes, int n_in,
                              void* d_out, int out_size, void* d_ws, size_t ws_size,
                              hipStream_t stream) {
  const float* x   = (const float*)d_in[0];
  const float* w1  = (const float*)d_in[1];
  const float* b1  = (const float*)d_in[2];
  const float* w2  = (const float*)d_in[3];
  const float* b2  = (const float*)d_in[4];
  const float* Wi  = (const float*)d_in[5];
  const float* Wh  = (const float*)d_in[6];
  const float* bia = (const float*)d_in[7];
  float* out = (float*)d_out;
  float* ws  = (float*)d_ws;

  float* scores = ws;                                    // 262144 f
  float* M      = ws + 262144;                           // 4194304 f
  unsigned long long* slab64 =
      (unsigned long long*)(ws + 262144 + 4194304);      // 2*64*4*64 u64

  hipLaunchKernelGGL(k_scores, dim3(8192), dim3(256), 0, stream,
                     x, w1, b1, w2, b2, scores);
  hipLaunchKernelGGL(k_attn_M, dim3(256), dim3(512), 0, stream,
                     x, scores, M, out);
  hipLaunchKernelGGL(k_lstm, dim3(256), dim3(1024), 0, stream,
                     M, Wi, Wh, bia, slab64, out);
}